// Round 5
// baseline (148.811 us; speedup 1.0000x reference)
//
#include <hip/hip_runtime.h>
#include <math.h>

// FourierFlow: out[t,n,i] = sum_j expm((M*omega + M0)*t)[i,j] * x[n,j]
// Inputs: x (16384,16) f32 | t (512,) f32 | omega (1,) f32 | M (16,16) f32 | M0 (16,16) f32
// Output: (512, 16384, 16) f32 = 536.9 MB -> write-BW bound (~85 us floor at 6.7 TB/s).

#define MDIM 16
#define MELEMS 256
#define RPT 16              // x-rows per thread in apply kernel
#define ROWS_PER_BLOCK 1024 // 64 lane-groups * RPT

typedef float f32x4 __attribute__((ext_vector_type(4)));

// ---------------- Kernel 1: batched 16x16 matrix exponential ----------------
// One block per time step, 256 threads (one per matrix element).
// Scaling-and-squaring + 8-term Horner-Taylor in LDS (||B||<=0.5 -> err ~1e-8).
__global__ __launch_bounds__(256) void expm_kernel(
    const float* __restrict__ t,
    const float* __restrict__ omega,
    const float* __restrict__ M,
    const float* __restrict__ M0,
    float* __restrict__ E /* (T,16,16) */) {
  __shared__ float A[MELEMS];
  __shared__ float T[MELEMS];
  __shared__ float rowsum[MDIM];

  const int bt  = blockIdx.x;
  const int tid = threadIdx.x;
  const int i = tid >> 4;
  const int j = tid & 15;

  const float tv = t[bt];
  const float om = omega[0];
  const float a = (M[tid] * om + M0[tid]) * tv;

  // parallel inf-norm: row-sum via 16-lane shuffle butterfly, then max over rows
  float rs = fabsf(a);
  rs += __shfl_xor(rs, 1);
  rs += __shfl_xor(rs, 2);
  rs += __shfl_xor(rs, 4);
  rs += __shfl_xor(rs, 8);
  if (j == 0) rowsum[i] = rs;
  __syncthreads();
  float nrm = 0.f;
#pragma unroll
  for (int r = 0; r < MDIM; ++r) nrm = fmaxf(nrm, rowsum[r]);
  // scaling exponent: nrm / 2^s <= 0.5
  int s = (nrm > 1e-30f) ? (ilogbf(nrm) + 2) : 0;
  if (s < 0) s = 0;

  const float b = ldexpf(a, -s);
  const float ident = (i == j) ? 1.0f : 0.0f;
  A[tid] = b;
  T[tid] = ident;
  __syncthreads();

  // Horner-Taylor: for k = K..1: T = I + (B @ T) / k
  for (int k = 8; k >= 1; --k) {
    float acc = 0.f;
#pragma unroll
    for (int c = 0; c < MDIM; ++c) acc += A[i * MDIM + c] * T[c * MDIM + j];
    __syncthreads();
    T[tid] = ident + acc * (1.0f / (float)k);
    __syncthreads();
  }

  // square s times
  for (int k = 0; k < s; ++k) {
    float acc = 0.f;
#pragma unroll
    for (int c = 0; c < MDIM; ++c) acc += T[i * MDIM + c] * T[c * MDIM + j];
    __syncthreads();
    T[tid] = acc;
    __syncthreads();
  }

  E[(size_t)bt * MELEMS + tid] = T[tid];
}

// ---------------- Kernel 2: out[t,n,:] = E[t] @ x[n,:] ----------------
// grid = (N/1024, T), block = 256. Thread (nl = tid>>2, i4 = tid&3) loads its
// 4 E-rows DIRECTLY from global into registers (L2-resident, 16-lane
// broadcast per address; no LDS, no barriers -> short prologue), then streams
// 16 x-rows through a 2-deep rotation: loads for row k+1 issue BEFORE the
// store of row k, so vmcnt waits never drain the HBM stores. Stores are
// non-temporal (write-once stream, skip LLC allocate).
__global__ __launch_bounds__(256, 4) void apply_kernel(
    const float* __restrict__ E,  /* (T,16,16) */
    const float* __restrict__ x,  /* (N,16)    */
    float* __restrict__ out,      /* (T,N,16)  */
    int N) {
  const int t   = blockIdx.y;
  const int tid = threadIdx.x;
  const int i4 = tid & 3;
  const int nl = tid >> 2;

  // 4 E-rows -> 16 float4 registers, straight from global
  float4 e[16];
  const float4* __restrict__ Er = (const float4*)(E + (size_t)t * MELEMS);
#pragma unroll
  for (int k = 0; k < 4; ++k)
#pragma unroll
    for (int q = 0; q < 4; ++q) e[k * 4 + q] = Er[(i4 * 4 + k) * 4 + q];

  const size_t nb = (size_t)blockIdx.x * ROWS_PER_BLOCK;
  const float4* __restrict__ xin = (const float4*)x;
  f32x4* __restrict__ op = (f32x4*)(out + ((size_t)t * N + nb) * MDIM);

  float4 xa0, xa1, xa2, xa3, xb0, xb1, xb2, xb3;

#define LOADX(d0, d1, d2, d3, k) do {                         \
    const size_t base = (nb + nl + (size_t)(k) * 64) * 4;     \
    d0 = xin[base + 0]; d1 = xin[base + 1];                   \
    d2 = xin[base + 2]; d3 = xin[base + 3];                   \
  } while (0)

#define DOT(o, x0, x1, x2, x3) do {                                        \
    _Pragma("unroll")                                                      \
    for (int r = 0; r < 4; ++r) {                                          \
      const float4 e0 = e[r * 4 + 0], e1 = e[r * 4 + 1];                   \
      const float4 e2 = e[r * 4 + 2], e3 = e[r * 4 + 3];                   \
      o[r] = e0.x * x0.x + e0.y * x0.y + e0.z * x0.z + e0.w * x0.w         \
           + e1.x * x1.x + e1.y * x1.y + e1.z * x1.z + e1.w * x1.w         \
           + e2.x * x2.x + e2.y * x2.y + e2.z * x2.z + e2.w * x2.w         \
           + e3.x * x3.x + e3.y * x3.y + e3.z * x3.z + e3.w * x3.w;        \
    }                                                                      \
  } while (0)

#define STORE_NT(idx, o) do {                                              \
    f32x4 v_; v_.x = (o)[0]; v_.y = (o)[1]; v_.z = (o)[2]; v_.w = (o)[3];  \
    __builtin_nontemporal_store(v_, &op[(idx)]);                           \
  } while (0)

  LOADX(xa0, xa1, xa2, xa3, 0);
#pragma unroll
  for (int k = 0; k < RPT; k += 2) {
    float o[4];
    // even row (in xa): prefetch k+1 into xb BEFORE storing row k
    if (k + 1 < RPT) LOADX(xb0, xb1, xb2, xb3, k + 1);
    DOT(o, xa0, xa1, xa2, xa3);
    STORE_NT(k * 256 + tid, o);
    // odd row (in xb): prefetch k+2 into xa BEFORE storing row k+1
    if (k + 2 < RPT) LOADX(xa0, xa1, xa2, xa3, k + 2);
    DOT(o, xb0, xb1, xb2, xb3);
    STORE_NT((k + 1) * 256 + tid, o);
  }
#undef LOADX
#undef DOT
#undef STORE_NT
}

extern "C" void kernel_launch(void* const* d_in, const int* in_sizes, int n_in,
                              void* d_out, int out_size, void* d_ws, size_t ws_size,
                              hipStream_t stream) {
  const float* x     = (const float*)d_in[0];
  const float* t     = (const float*)d_in[1];
  const float* omega = (const float*)d_in[2];
  const float* M     = (const float*)d_in[3];
  const float* M0    = (const float*)d_in[4];
  float* out = (float*)d_out;

  const int N = in_sizes[0] / MDIM;   // 16384
  const int T = in_sizes[1];          // 512

  float* E = (float*)d_ws;            // T*256 floats = 512 KB

  expm_kernel<<<T, 256, 0, stream>>>(t, omega, M, M0, E);

  dim3 grid(N / ROWS_PER_BLOCK, T);
  apply_kernel<<<grid, 256, 0, stream>>>(E, x, out, N);
}

// Round 6
// 116.904 us; speedup vs baseline: 1.2729x; 1.2729x over previous
//
#include <hip/hip_runtime.h>
#include <math.h>

// FourierFlow: out[t,n,i] = sum_j expm((M*omega + M0)*t)[i,j] * x[n,j]
// Inputs: x (16384,16) f32 | t (512,) f32 | omega (1,) f32 | M (16,16) f32 | M0 (16,16) f32
// Output: (512, 16384, 16) f32 = 536.9 MB -> write-BW bound (~85 us floor at 6.7 TB/s).

#define MDIM 16
#define MELEMS 256
#define BLOCKS_PER_T 4
#define ROWS_PER_BLOCK 4096   // N / BLOCKS_PER_T
#define KSTEPS 64             // ROWS_PER_BLOCK / 64 lane-groups

// ---------------- Kernel 1: batched 16x16 matrix exponential ----------------
// One block per time step, 256 threads (one per matrix element).
// Scaling-and-squaring + 8-term Horner-Taylor in LDS (||B||<=0.5 -> err ~1e-8).
__global__ __launch_bounds__(256) void expm_kernel(
    const float* __restrict__ t,
    const float* __restrict__ omega,
    const float* __restrict__ M,
    const float* __restrict__ M0,
    float* __restrict__ E /* (T,16,16) */) {
  __shared__ float A[MELEMS];
  __shared__ float T[MELEMS];
  __shared__ float rowsum[MDIM];

  const int bt  = blockIdx.x;
  const int tid = threadIdx.x;
  const int i = tid >> 4;
  const int j = tid & 15;

  const float tv = t[bt];
  const float om = omega[0];
  const float a = (M[tid] * om + M0[tid]) * tv;

  // parallel inf-norm: row-sum via 16-lane shuffle butterfly, then max over rows
  float rs = fabsf(a);
  rs += __shfl_xor(rs, 1);
  rs += __shfl_xor(rs, 2);
  rs += __shfl_xor(rs, 4);
  rs += __shfl_xor(rs, 8);
  if (j == 0) rowsum[i] = rs;
  __syncthreads();
  float nrm = 0.f;
#pragma unroll
  for (int r = 0; r < MDIM; ++r) nrm = fmaxf(nrm, rowsum[r]);
  // scaling exponent: nrm / 2^s <= 0.5
  int s = (nrm > 1e-30f) ? (ilogbf(nrm) + 2) : 0;
  if (s < 0) s = 0;

  const float b = ldexpf(a, -s);
  const float ident = (i == j) ? 1.0f : 0.0f;
  A[tid] = b;
  T[tid] = ident;
  __syncthreads();

  // Horner-Taylor: for k = K..1: T = I + (B @ T) / k
  for (int k = 8; k >= 1; --k) {
    float acc = 0.f;
#pragma unroll
    for (int c = 0; c < MDIM; ++c) acc += A[i * MDIM + c] * T[c * MDIM + j];
    __syncthreads();
    T[tid] = ident + acc * (1.0f / (float)k);
    __syncthreads();
  }

  // square s times
  for (int k = 0; k < s; ++k) {
    float acc = 0.f;
#pragma unroll
    for (int c = 0; c < MDIM; ++c) acc += T[i * MDIM + c] * T[c * MDIM + j];
    __syncthreads();
    T[tid] = acc;
    __syncthreads();
  }

  E[(size_t)bt * MELEMS + tid] = T[tid];
}

// ---------------- Kernel 2: out[t,n,:] = E[t] @ x[n,:] ----------------
// 2048 big blocks, 4 per t; each owns 4096 consecutive rows of one t-slice.
// Thread (nl = tid>>2, i4 = tid&3) loads its 4 E-rows ONCE from global
// (LLC-resident, one-time cost amortized over 64 rows/thread; no LDS, no
// barriers), then runs one continuous 64-row 2-deep rotation: loads for row
// k+1 always issue BEFORE the store of row k, so vmcnt waits on the (cached)
// x loads never force HBM-store drains. Stores are plain dwordx4, perfectly
// coalesced (consecutive tid -> consecutive 16B).
__global__ __launch_bounds__(256, 4) void apply_kernel(
    const float* __restrict__ E,  /* (T,16,16) */
    const float* __restrict__ x,  /* (N,16)    */
    float* __restrict__ out,      /* (T,N,16)  */
    int N) {
  const int blk = blockIdx.x;
  const int t   = blk >> 2;                    // 4 blocks per t
  const int tid = threadIdx.x;
  const int i4 = tid & 3;
  const int nl = tid >> 2;

  // 4 E-rows -> 16 float4 registers, straight from global (once per block)
  float4 e[16];
  const float4* __restrict__ Er = (const float4*)(E + (size_t)t * MELEMS);
#pragma unroll
  for (int k = 0; k < 4; ++k)
#pragma unroll
    for (int q = 0; q < 4; ++q) e[k * 4 + q] = Er[(i4 * 4 + k) * 4 + q];

  const size_t base = (size_t)(blk & 3) * ROWS_PER_BLOCK;  // row base in t-slice
  const float4* __restrict__ xin = (const float4*)x;
  float4* __restrict__ op = (float4*)(out + ((size_t)t * N + base) * MDIM);

  float4 xa0, xa1, xa2, xa3, xb0, xb1, xb2, xb3;

#define LOADX(d0, d1, d2, d3, k) do {                         \
    const size_t b_ = (base + nl + (size_t)(k) * 64) * 4;     \
    d0 = xin[b_ + 0]; d1 = xin[b_ + 1];                       \
    d2 = xin[b_ + 2]; d3 = xin[b_ + 3];                       \
  } while (0)

#define DOT(o, x0, x1, x2, x3) do {                                        \
    _Pragma("unroll")                                                      \
    for (int r = 0; r < 4; ++r) {                                          \
      const float4 e0 = e[r * 4 + 0], e1 = e[r * 4 + 1];                   \
      const float4 e2 = e[r * 4 + 2], e3 = e[r * 4 + 3];                   \
      o[r] = e0.x * x0.x + e0.y * x0.y + e0.z * x0.z + e0.w * x0.w         \
           + e1.x * x1.x + e1.y * x1.y + e1.z * x1.z + e1.w * x1.w         \
           + e2.x * x2.x + e2.y * x2.y + e2.z * x2.z + e2.w * x2.w         \
           + e3.x * x3.x + e3.y * x3.y + e3.z * x3.z + e3.w * x3.w;        \
    }                                                                      \
  } while (0)

  LOADX(xa0, xa1, xa2, xa3, 0);
#pragma unroll 4
  for (int k = 0; k < KSTEPS; k += 2) {
    float o[4];
    // even row (in xa): prefetch k+1 into xb BEFORE storing row k
    LOADX(xb0, xb1, xb2, xb3, k + 1);
    DOT(o, xa0, xa1, xa2, xa3);
    op[k * 256 + tid] = make_float4(o[0], o[1], o[2], o[3]);
    // odd row (in xb): prefetch k+2 into xa BEFORE storing row k+1
    if (k + 2 < KSTEPS) LOADX(xa0, xa1, xa2, xa3, k + 2);
    DOT(o, xb0, xb1, xb2, xb3);
    op[(k + 1) * 256 + tid] = make_float4(o[0], o[1], o[2], o[3]);
  }
#undef LOADX
#undef DOT
}

extern "C" void kernel_launch(void* const* d_in, const int* in_sizes, int n_in,
                              void* d_out, int out_size, void* d_ws, size_t ws_size,
                              hipStream_t stream) {
  const float* x     = (const float*)d_in[0];
  const float* t     = (const float*)d_in[1];
  const float* omega = (const float*)d_in[2];
  const float* M     = (const float*)d_in[3];
  const float* M0    = (const float*)d_in[4];
  float* out = (float*)d_out;

  const int N = in_sizes[0] / MDIM;   // 16384
  const int T = in_sizes[1];          // 512

  float* E = (float*)d_ws;            // T*256 floats = 512 KB

  expm_kernel<<<T, 256, 0, stream>>>(t, omega, M, M0, E);

  apply_kernel<<<T * BLOCKS_PER_T, 256, 0, stream>>>(E, x, out, N);
}